// Round 2
// baseline (16284.908 us; speedup 1.0000x reference)
//
#include <hip/hip_runtime.h>
#include <math.h>

#define NB 4
#define SS 2048
#define HH 512
#define NHD 8
#define HD 64
#define CSHIFT 24.0f   // fixed softmax shift: exact (scores bounded << 24), no max pass

// ---------------------------------------------------------------------------
// GEMM: out[m][n] = sum_k A[m][k] * W[n][k] + bias[n]   (A @ W^T + b)
// A: [M x 512] row-major, W: [N x 512] row-major.
// Tile 128x128, BK=32, 256 threads, 8x8 micro-tile (1 B LDS per FMA-lane).
// Lane map: rows ty+16i, cols tx+16j  -> all LDS reads 2-way/broadcast (free).
// mode 0: N=1536, scatter into qkv[3][B][NH][S][HD];  mode 1: plain [M x 512].
// ---------------------------------------------------------------------------
__global__ __launch_bounds__(256, 3) void gemm_kernel(
    const float* __restrict__ A, const float* __restrict__ W,
    const float* __restrict__ bias, float* __restrict__ out, int mode) {
  __shared__ __align__(16) float As[128][36];
  __shared__ __align__(16) float Bs[128][36];
  const int t = threadIdx.x;
  const int m0 = blockIdx.x * 128;
  const int n0 = blockIdx.y * 128;
  const int tx = t & 15, ty = t >> 4;
  const int lr = t >> 1;            // stage row 0..127
  const int lc = (t & 1) * 16;      // stage col 0 or 16

  float acc[8][8] = {};
  for (int k0 = 0; k0 < 512; k0 += 32) {
    const float* ap = A + (size_t)(m0 + lr) * 512 + k0 + lc;
    const float* wp = W + (size_t)(n0 + lr) * 512 + k0 + lc;
    float4 a0 = *(const float4*)ap;
    float4 a1 = *(const float4*)(ap + 4);
    float4 a2 = *(const float4*)(ap + 8);
    float4 a3 = *(const float4*)(ap + 12);
    float4 b0 = *(const float4*)wp;
    float4 b1 = *(const float4*)(wp + 4);
    float4 b2 = *(const float4*)(wp + 8);
    float4 b3 = *(const float4*)(wp + 12);
    __syncthreads();
    *(float4*)&As[lr][lc]      = a0;
    *(float4*)&As[lr][lc + 4]  = a1;
    *(float4*)&As[lr][lc + 8]  = a2;
    *(float4*)&As[lr][lc + 12] = a3;
    *(float4*)&Bs[lr][lc]      = b0;
    *(float4*)&Bs[lr][lc + 4]  = b1;
    *(float4*)&Bs[lr][lc + 8]  = b2;
    *(float4*)&Bs[lr][lc + 12] = b3;
    __syncthreads();
#pragma unroll
    for (int kk = 0; kk < 32; kk += 4) {
      float4 av[8], bv[8];
#pragma unroll
      for (int i = 0; i < 8; ++i) av[i] = *(const float4*)&As[ty + 16 * i][kk];
#pragma unroll
      for (int j = 0; j < 8; ++j) bv[j] = *(const float4*)&Bs[tx + 16 * j][kk];
#pragma unroll
      for (int i = 0; i < 8; ++i)
#pragma unroll
        for (int j = 0; j < 8; ++j)
          acc[i][j] += av[i].x * bv[j].x + av[i].y * bv[j].y +
                       av[i].z * bv[j].z + av[i].w * bv[j].w;
    }
  }

  float bj[8];
#pragma unroll
  for (int j = 0; j < 8; ++j) bj[j] = bias[n0 + tx + 16 * j];

  if (mode == 0) {
    const size_t QSZ = (size_t)NB * NHD * SS * HD;
#pragma unroll
    for (int i = 0; i < 8; ++i) {
      int row = m0 + ty + 16 * i;
      int b = row >> 11, srow = row & 2047;
#pragma unroll
      for (int j = 0; j < 8; ++j) {
        int c = n0 + tx + 16 * j;
        int which = c >> 9, h = (c >> 6) & 7, d = c & 63;
        out[which * QSZ + ((size_t)(b * NHD + h) * SS + srow) * HD + d] =
            acc[i][j] + bj[j];
      }
    }
  } else {
#pragma unroll
    for (int i = 0; i < 8; ++i) {
      int row = m0 + ty + 16 * i;
#pragma unroll
      for (int j = 0; j < 8; ++j)
        out[(size_t)row * HH + n0 + tx + 16 * j] = acc[i][j] + bj[j];
    }
  }
}

// ---------------------------------------------------------------------------
// Kernel 2: linv[b][h][q] = 1 / sum_k mask[k] * exp((q.k - d2)*0.125 - C)
// grid (B*NH, S/64); q-tile 64, k-tile 128, micro 4x8 (1.5 B/FMA).
// ---------------------------------------------------------------------------
__global__ __launch_bounds__(256, 3) void lsum_kernel(
    const float* __restrict__ qkv, const float* __restrict__ positions,
    const int* __restrict__ amask, float* __restrict__ linv) {
  __shared__ __align__(16) float Qs[64][68];
  __shared__ __align__(16) float Ks[128][68];
  const int bh = blockIdx.x;
  const int b = bh >> 3;
  const int q0 = blockIdx.y * 64;
  const int t = threadIdx.x;
  const int tx = t & 15, ty = t >> 4;
  const float* Qg = qkv + ((size_t)bh * SS + q0) * HD;
  const float* Kg = qkv + (size_t)NB * NHD * SS * HD + (size_t)bh * SS * HD;

  {  // stage Q once: 64 rows x 64 cols
    int r = t >> 2, c = (t & 3) * 16;
    const float* qp = Qg + (size_t)r * HD + c;
#pragma unroll
    for (int u = 0; u < 4; ++u)
      *(float4*)&Qs[r][c + 4 * u] = *(const float4*)(qp + 4 * u);
  }
  float pq[4][3];
#pragma unroll
  for (int i = 0; i < 4; ++i) {
    const float* pp = positions + ((size_t)b * SS + q0 + ty + 16 * i) * 3;
    pq[i][0] = pp[0]; pq[i][1] = pp[1]; pq[i][2] = pp[2];
  }

  float ls[4] = {0.f, 0.f, 0.f, 0.f};
  for (int kt = 0; kt < SS; kt += 128) {
    __syncthreads();
    {  // stage K tile 128x64
      int r = t >> 1, c = (t & 1) * 32;
      const float* kp = Kg + (size_t)(kt + r) * HD + c;
#pragma unroll
      for (int u = 0; u < 8; ++u)
        *(float4*)&Ks[r][c + 4 * u] = *(const float4*)(kp + 4 * u);
    }
    __syncthreads();
    float sc[4][8] = {};
#pragma unroll
    for (int d = 0; d < 64; d += 4) {
      float4 qa[4], kv[8];
#pragma unroll
      for (int i = 0; i < 4; ++i) qa[i] = *(const float4*)&Qs[ty + 16 * i][d];
#pragma unroll
      for (int j = 0; j < 8; ++j) kv[j] = *(const float4*)&Ks[tx + 16 * j][d];
#pragma unroll
      for (int i = 0; i < 4; ++i)
#pragma unroll
        for (int j = 0; j < 8; ++j)
          sc[i][j] += qa[i].x * kv[j].x + qa[i].y * kv[j].y +
                      qa[i].z * kv[j].z + qa[i].w * kv[j].w;
    }
#pragma unroll
    for (int j = 0; j < 8; ++j) {
      int kk = kt + tx + 16 * j;
      const float* pp = positions + ((size_t)b * SS + kk) * 3;
      float px = pp[0], py = pp[1], pz = pp[2];
      int mval = amask[(size_t)b * SS + kk];
      if (mval) {
#pragma unroll
        for (int i = 0; i < 4; ++i) {
          float dx = pq[i][0] - px, dy = pq[i][1] - py, dz = pq[i][2] - pz;
          float d2 = dx * dx + dy * dy + dz * dz;
          ls[i] += __expf((sc[i][j] - d2) * 0.125f - CSHIFT);
        }
      }
    }
  }
  // reduce across tx: reuse Ks storage as scratch
  __syncthreads();
  float* red = &Ks[0][0];  // need 64*16 floats
#pragma unroll
  for (int i = 0; i < 4; ++i) red[(ty + 16 * i) * 16 + tx] = ls[i];
  __syncthreads();
  if (t < 64) {
    float s = 0.f;
#pragma unroll
    for (int u = 0; u < 16; ++u) s += red[t * 16 + u];
    linv[(size_t)bh * SS + q0 + t] = 1.0f / fmaxf(s, 1e-30f);
  }
}

// ---------------------------------------------------------------------------
// Kernel 3: grid (S/64, B, S/64): block owns (q-tile 64, b, k-tile 64).
// h looped inside (rolled): per h stage Q/K/V, QK 4x4 micro, p=exp*er*linv,
// Ps overwrites Qs buffer, PV 4x4; O[4][4] atomically added into ao.
// attn_mean accumulated over h in registers, written once (exclusive tile).
// ---------------------------------------------------------------------------
__global__ __launch_bounds__(256, 3) void attn_kernel(
    const float* __restrict__ qkv, const float* __restrict__ positions,
    const int* __restrict__ amask, const float* __restrict__ linv,
    float* __restrict__ ao, float* __restrict__ mean_out) {
  __shared__ __align__(16) float QPs[64][68];   // Q, then reused for P
  __shared__ __align__(16) float Ks[64][68];
  __shared__ __align__(16) float Vs[64][64];    // col-group rotated by row
  __shared__ float linvs[NHD][64];
  const int b = blockIdx.y;
  const int q0 = blockIdx.x * 64;
  const int kt = blockIdx.z * 64;
  const int t = threadIdx.x;
  const int tx = t & 15, ty = t >> 4;
  const float* Qg = qkv;
  const float* Kg = qkv + (size_t)NB * NHD * SS * HD;
  const float* Vg = Kg + (size_t)NB * NHD * SS * HD;

  {  // 512 linv values
    int i0 = t, i1 = t + 256;
    linvs[i0 >> 6][i0 & 63] = linv[(size_t)(b * NHD + (i0 >> 6)) * SS + q0 + (i0 & 63)];
    linvs[i1 >> 6][i1 & 63] = linv[(size_t)(b * NHD + (i1 >> 6)) * SS + q0 + (i1 & 63)];
  }
  float pq[4][3];
#pragma unroll
  for (int i = 0; i < 4; ++i) {
    const float* pp = positions + ((size_t)b * SS + q0 + ty + 16 * i) * 3;
    pq[i][0] = pp[0]; pq[i][1] = pp[1]; pq[i][2] = pp[2];
  }
  // h-invariant masked locality factor for this (q-tile, k-tile)
  float er[4][4];
#pragma unroll
  for (int j = 0; j < 4; ++j) {
    int kk = kt + tx + 16 * j;
    const float* pp = positions + ((size_t)b * SS + kk) * 3;
    float px = pp[0], py = pp[1], pz = pp[2];
    int mval = amask[(size_t)b * SS + kk];
#pragma unroll
    for (int i = 0; i < 4; ++i) {
      float dx = pq[i][0] - px, dy = pq[i][1] - py, dz = pq[i][2] - pz;
      float d2 = dx * dx + dy * dy + dz * dz;
      er[i][j] = mval ? __expf(-0.125f * d2) : 0.f;
    }
  }

  float am[4][4] = {};
  const int sr = t >> 2;           // stage row 0..63
  const int scol = (t & 3) * 16;   // stage col

  for (int h = 0; h < NHD; ++h) {
    __syncthreads();  // previous iteration's LDS reads complete
    {
      const float* qp = Qg + ((size_t)(b * NHD + h) * SS + q0 + sr) * HD + scol;
      const float* kp = Kg + ((size_t)(b * NHD + h) * SS + kt + sr) * HD + scol;
      const float* vp = Vg + ((size_t)(b * NHD + h) * SS + kt + sr) * HD + scol;
#pragma unroll
      for (int u = 0; u < 4; ++u) {
        *(float4*)&QPs[sr][scol + 4 * u] = *(const float4*)(qp + 4 * u);
        *(float4*)&Ks[sr][scol + 4 * u]  = *(const float4*)(kp + 4 * u);
        int cg = (t & 3) * 4 + u;                 // logical col-group
        int pg = (cg + sr) & 15;                  // rotated physical group
        *(float4*)&Vs[sr][pg * 4] = *(const float4*)(vp + 4 * u);
      }
    }
    __syncthreads();

    float sc[4][4] = {};
#pragma unroll
    for (int d = 0; d < 64; d += 4) {
      float4 qa[4], kv[4];
#pragma unroll
      for (int i = 0; i < 4; ++i) qa[i] = *(const float4*)&QPs[ty + 16 * i][d];
#pragma unroll
      for (int j = 0; j < 4; ++j) kv[j] = *(const float4*)&Ks[tx + 16 * j][d];
#pragma unroll
      for (int i = 0; i < 4; ++i)
#pragma unroll
        for (int j = 0; j < 4; ++j)
          sc[i][j] += qa[i].x * kv[j].x + qa[i].y * kv[j].y +
                      qa[i].z * kv[j].z + qa[i].w * kv[j].w;
    }

    float p[4][4];
#pragma unroll
    for (int i = 0; i < 4; ++i) {
      float li = linvs[h][ty + 16 * i];
#pragma unroll
      for (int j = 0; j < 4; ++j) {
        p[i][j] = __expf(sc[i][j] * 0.125f - CSHIFT) * er[i][j] * li;
        am[i][j] += p[i][j] * 0.125f;  // 1/NH
      }
    }
    __syncthreads();  // everyone done reading Q before overwrite with P
#pragma unroll
    for (int i = 0; i < 4; ++i)
#pragma unroll
      for (int j = 0; j < 4; ++j)
        QPs[ty + 16 * i][tx + 16 * j] = p[i][j];
    __syncthreads();  // P visible

    float O[4][4] = {};
#pragma unroll
    for (int kk = 0; kk < 64; kk += 4) {
      float4 pa[4];
#pragma unroll
      for (int i = 0; i < 4; ++i) pa[i] = *(const float4*)&QPs[ty + 16 * i][kk];
#pragma unroll
      for (int u = 0; u < 4; ++u) {
        int rr = kk + u;
        float4 vv = *(const float4*)&Vs[rr][((tx + rr) & 15) * 4];
        float w0 = pa[0].x, w1 = pa[1].x, w2 = pa[2].x, w3 = pa[3].x;
        float pw[4] = { (&pa[0].x)[u], (&pa[1].x)[u], (&pa[2].x)[u], (&pa[3].x)[u] };
        (void)w0; (void)w1; (void)w2; (void)w3;
        O[0][0] += pw[0] * vv.x; O[0][1] += pw[0] * vv.y;
        O[0][2] += pw[0] * vv.z; O[0][3] += pw[0] * vv.w;
        O[1][0] += pw[1] * vv.x; O[1][1] += pw[1] * vv.y;
        O[1][2] += pw[1] * vv.z; O[1][3] += pw[1] * vv.w;
        O[2][0] += pw[2] * vv.x; O[2][1] += pw[2] * vv.y;
        O[2][2] += pw[2] * vv.z; O[2][3] += pw[2] * vv.w;
        O[3][0] += pw[3] * vv.x; O[3][1] += pw[3] * vv.y;
        O[3][2] += pw[3] * vv.z; O[3][3] += pw[3] * vv.w;
      }
    }
#pragma unroll
    for (int i = 0; i < 4; ++i) {
      float* dst = ao + ((size_t)b * SS + q0 + ty + 16 * i) * HH + h * HD + 4 * tx;
      atomicAdd(dst + 0, O[i][0]);
      atomicAdd(dst + 1, O[i][1]);
      atomicAdd(dst + 2, O[i][2]);
      atomicAdd(dst + 3, O[i][3]);
    }
  }  // h

#pragma unroll
  for (int i = 0; i < 4; ++i)
#pragma unroll
    for (int j = 0; j < 4; ++j)
      mean_out[((size_t)b * SS + q0 + ty + 16 * i) * SS + kt + tx + 16 * j] =
          am[i][j];
}

// ---------------------------------------------------------------------------
extern "C" void kernel_launch(void* const* d_in, const int* in_sizes, int n_in,
                              void* d_out, int out_size, void* d_ws,
                              size_t ws_size, hipStream_t stream) {
  const float* x         = (const float*)d_in[0];
  const float* positions = (const float*)d_in[1];
  const int*   amask     = (const int*)d_in[2];
  const float* w_qkv     = (const float*)d_in[3];
  const float* b_qkv     = (const float*)d_in[4];
  const float* w_out     = (const float*)d_in[5];
  const float* b_out     = (const float*)d_in[6];

  float* out      = (float*)d_out;                // [B,S,H]
  float* mean_out = out + (size_t)NB * SS * HH;   // [B,S,S]

  // ws (floats): qkv[3][B][NH][S][HD] | linv[B*NH*S] | ao[B,S,H] = 67.4 MB
  float* ws   = (float*)d_ws;
  const size_t QSZ = (size_t)NB * NHD * SS * HD;  // 4,194,304
  float* qkv  = ws;
  float* linv = ws + 3 * QSZ;
  float* ao   = linv + (size_t)NB * NHD * SS;

  dim3 blk(256);
  gemm_kernel<<<dim3(64, 12), blk, 0, stream>>>(x, w_qkv, b_qkv, qkv, 0);
  lsum_kernel<<<dim3(32, 32), blk, 0, stream>>>(qkv, positions, amask, linv);
  hipMemsetAsync(ao, 0, QSZ * sizeof(float), stream);
  attn_kernel<<<dim3(32, NB, 32), blk, 0, stream>>>(qkv, positions, amask,
                                                    linv, ao, mean_out);
  gemm_kernel<<<dim3(64, 4), blk, 0, stream>>>(ao, w_out, b_out, out, 1);
}

// Round 3
// 1406.684 us; speedup vs baseline: 11.5768x; 11.5768x over previous
//
#include <hip/hip_runtime.h>
#include <math.h>

#define NB 4
#define SS 2048
#define HH 512
#define NHD 8
#define HD 64
#define CSHIFT 24.0f   // fixed softmax shift: exact (|scores| < ~8), no max pass

// ---------------------------------------------------------------------------
// GEMM (r1-proven): out[m][n] = sum_k A[m][k]*W[n][k] + bias[n]  (A @ W^T + b)
// Tile 64x64, BK=32, 256 threads, 4x4 micro-tile.
// mode 0: N=1536, scatter into qkv[3][B][NH][S][HD];  mode 1: plain [M x 512].
// ---------------------------------------------------------------------------
__global__ __launch_bounds__(256) void gemm_kernel(
    const float* __restrict__ A, const float* __restrict__ W,
    const float* __restrict__ bias, float* __restrict__ out, int mode) {
  __shared__ __align__(16) float As[64][36];
  __shared__ __align__(16) float Bs[64][36];
  const int t = threadIdx.x;
  const int m0 = blockIdx.x * 64;
  const int n0 = blockIdx.y * 64;
  const int tx = t & 15, ty = t >> 4;
  const int lr = t >> 2;
  const int lc = (t & 3) * 8;

  float acc[4][4] = {};
  for (int k0 = 0; k0 < 512; k0 += 32) {
    const float* ap = A + (size_t)(m0 + lr) * 512 + k0 + lc;
    float4 a0 = *(const float4*)ap;
    float4 a1 = *(const float4*)(ap + 4);
    const float* wp = W + (size_t)(n0 + lr) * 512 + k0 + lc;
    float4 b0 = *(const float4*)wp;
    float4 b1 = *(const float4*)(wp + 4);
    __syncthreads();
    *(float4*)&As[lr][lc]     = a0;
    *(float4*)&As[lr][lc + 4] = a1;
    *(float4*)&Bs[lr][lc]     = b0;
    *(float4*)&Bs[lr][lc + 4] = b1;
    __syncthreads();
#pragma unroll 2
    for (int kk = 0; kk < 32; kk += 4) {
      float4 av[4], bv[4];
#pragma unroll
      for (int i = 0; i < 4; ++i) av[i] = *(const float4*)&As[ty * 4 + i][kk];
#pragma unroll
      for (int j = 0; j < 4; ++j) bv[j] = *(const float4*)&Bs[tx * 4 + j][kk];
#pragma unroll
      for (int i = 0; i < 4; ++i)
#pragma unroll
        for (int j = 0; j < 4; ++j)
          acc[i][j] += av[i].x * bv[j].x + av[i].y * bv[j].y +
                       av[i].z * bv[j].z + av[i].w * bv[j].w;
    }
  }

  float4 bb = *(const float4*)&bias[n0 + tx * 4];
  if (mode == 0) {
    const int which = n0 >> 9;
    const int h = (n0 & 511) >> 6;
    const int b = m0 >> 11;
    const int srow = m0 & 2047;
    float* qbase = out + (size_t)which * ((size_t)NB * NHD * SS * HD) +
                   ((size_t)(b * NHD + h) * SS) * HD;
#pragma unroll
    for (int i = 0; i < 4; ++i) {
      float4 r;
      r.x = acc[i][0] + bb.x; r.y = acc[i][1] + bb.y;
      r.z = acc[i][2] + bb.z; r.w = acc[i][3] + bb.w;
      *(float4*)&qbase[(size_t)(srow + ty * 4 + i) * HD + tx * 4] = r;
    }
  } else {
#pragma unroll
    for (int i = 0; i < 4; ++i) {
      float4 r;
      r.x = acc[i][0] + bb.x; r.y = acc[i][1] + bb.y;
      r.z = acc[i][2] + bb.z; r.w = acc[i][3] + bb.w;
      *(float4*)&out[(size_t)(m0 + ty * 4 + i) * HH + n0 + tx * 4] = r;
    }
  }
}

// ---------------------------------------------------------------------------
// attn_O: block = (q-tile 32, b, h). Single kt sweep accumulating
// UNNORMALIZED O (p = exp((qk-d2)/8 - C), mask folded as d2 = +huge) and
// row-sums l; epilogue scales O by 1/l, writes ao + linv. No atomics.
// ---------------------------------------------------------------------------
__global__ __launch_bounds__(256) void attn_o_kernel(
    const float* __restrict__ qkv, const float* __restrict__ positions,
    const int* __restrict__ amask, float* __restrict__ ao,
    float* __restrict__ linv) {
  __shared__ __align__(16) float Qs[32][68];
  __shared__ __align__(16) float KPs[64][68];   // K tile, then P overwrites
  __shared__ __align__(16) float Vs[64][64];    // col-group rotated by row
  __shared__ float red[32][17];
  __shared__ float linv_s[32];
  const int q0 = blockIdx.x * 32;
  const int b  = blockIdx.y;
  const int h  = blockIdx.z;
  const int t = threadIdx.x;
  const int tx = t & 15, ty = t >> 4;
  const size_t QSZ = (size_t)NB * NHD * SS * HD;
  const float* Qg = qkv + (size_t)(b * NHD + h) * SS * HD;
  const float* Kg = Qg + QSZ;
  const float* Vg = Qg + 2 * QSZ;

  {  // stage Q 32x64 once
    int r = t >> 3, c = (t & 7) * 8;
    const float* qp = Qg + (size_t)(q0 + r) * HD + c;
    *(float4*)&Qs[r][c]     = *(const float4*)qp;
    *(float4*)&Qs[r][c + 4] = *(const float4*)(qp + 4);
  }
  float pq[2][3];
#pragma unroll
  for (int i = 0; i < 2; ++i) {
    const float* pp = positions + ((size_t)b * SS + q0 + ty + 16 * i) * 3;
    pq[i][0] = pp[0]; pq[i][1] = pp[1]; pq[i][2] = pp[2];
  }

  float O[2][4] = {};
  float ls[2] = {0.f, 0.f};
  const int sr = t >> 2, scol = (t & 3) * 16;

  for (int kt = 0; kt < SS; kt += 64) {
    // masked squared distances for this thread's 4 k-cols (h-free)
    float d2m[2][4];
#pragma unroll
    for (int j = 0; j < 4; ++j) {
      int kk = kt + tx + 16 * j;
      const float* pp = positions + ((size_t)b * SS + kk) * 3;
      float px = pp[0], py = pp[1], pz = pp[2];
      int mval = amask[(size_t)b * SS + kk];
#pragma unroll
      for (int i = 0; i < 2; ++i) {
        float dx = pq[i][0] - px, dy = pq[i][1] - py, dz = pq[i][2] - pz;
        float d2 = dx * dx + dy * dy + dz * dz;
        d2m[i][j] = mval ? d2 : 3.0e8f;   // exp underflows to exactly 0
      }
    }
    __syncthreads();  // previous iter's KPs/Vs reads complete
    {
      const float* kp = Kg + (size_t)(kt + sr) * HD + scol;
      const float* vp = Vg + (size_t)(kt + sr) * HD + scol;
#pragma unroll
      for (int u = 0; u < 4; ++u) {
        *(float4*)&KPs[sr][scol + 4 * u] = *(const float4*)(kp + 4 * u);
        int cg = (t & 3) * 4 + u;
        int pg = (cg + sr) & 15;
        *(float4*)&Vs[sr][pg * 4] = *(const float4*)(vp + 4 * u);
      }
    }
    __syncthreads();

    float sc[2][4] = {};
#pragma unroll 2
    for (int d = 0; d < 64; d += 4) {
      float4 qa[2], kv[4];
#pragma unroll
      for (int i = 0; i < 2; ++i) qa[i] = *(const float4*)&Qs[ty + 16 * i][d];
#pragma unroll
      for (int j = 0; j < 4; ++j) kv[j] = *(const float4*)&KPs[tx + 16 * j][d];
#pragma unroll
      for (int i = 0; i < 2; ++i)
#pragma unroll
        for (int j = 0; j < 4; ++j)
          sc[i][j] += qa[i].x * kv[j].x + qa[i].y * kv[j].y +
                      qa[i].z * kv[j].z + qa[i].w * kv[j].w;
    }

    float p[2][4];
#pragma unroll
    for (int i = 0; i < 2; ++i)
#pragma unroll
      for (int j = 0; j < 4; ++j) {
        p[i][j] = __expf((sc[i][j] - d2m[i][j]) * 0.125f - CSHIFT);
        ls[i] += p[i][j];
      }
    __syncthreads();  // all QK reads of K done before P overwrite
#pragma unroll
    for (int i = 0; i < 2; ++i)
#pragma unroll
      for (int j = 0; j < 4; ++j)
        KPs[ty + 16 * i][tx + 16 * j] = p[i][j];
    __syncthreads();

#pragma unroll 2
    for (int kk = 0; kk < 64; kk += 4) {
      float4 pa[2];
#pragma unroll
      for (int i = 0; i < 2; ++i) pa[i] = *(const float4*)&KPs[ty + 16 * i][kk];
#pragma unroll
      for (int u = 0; u < 4; ++u) {
        int rr = kk + u;
        float4 vv = *(const float4*)&Vs[rr][((tx + rr) & 15) * 4];
        float w0 = (&pa[0].x)[u], w1 = (&pa[1].x)[u];
        O[0][0] += w0 * vv.x; O[0][1] += w0 * vv.y;
        O[0][2] += w0 * vv.z; O[0][3] += w0 * vv.w;
        O[1][0] += w1 * vv.x; O[1][1] += w1 * vv.y;
        O[1][2] += w1 * vv.z; O[1][3] += w1 * vv.w;
      }
    }
  }  // kt

  red[ty][tx]      = ls[0];
  red[ty + 16][tx] = ls[1];
  __syncthreads();
  if (t < 32) {
    float s = 0.f;
#pragma unroll
    for (int u = 0; u < 16; ++u) s += red[t][u];
    float li = 1.0f / fmaxf(s, 1e-30f);
    linv_s[t] = li;
    linv[(size_t)(b * NHD + h) * SS + q0 + t] = li;
  }
  __syncthreads();
#pragma unroll
  for (int i = 0; i < 2; ++i) {
    float li = linv_s[ty + 16 * i];
    float4 o4;
    o4.x = O[i][0] * li; o4.y = O[i][1] * li;
    o4.z = O[i][2] * li; o4.w = O[i][3] * li;
    *(float4*)&ao[((size_t)b * SS + q0 + ty + 16 * i) * HH + h * HD + 4 * tx] =
        o4;
  }
}

// ---------------------------------------------------------------------------
// attn_mean: block = (q-tile 64, b, ks of 8); kt = ks*256 + {0,64,128,192}.
// h looped inside; am accumulated in regs; exclusive mean writes. No atomics.
// ---------------------------------------------------------------------------
__global__ __launch_bounds__(256) void mean_kernel(
    const float* __restrict__ qkv, const float* __restrict__ positions,
    const int* __restrict__ amask, const float* __restrict__ linv,
    float* __restrict__ mean_out) {
  __shared__ __align__(16) float Qs[64][68];
  __shared__ __align__(16) float Ks[64][68];
  __shared__ float linvs[NHD][64];
  const int q0 = blockIdx.x * 64;
  const int b  = blockIdx.y;
  const int ks = blockIdx.z;
  const int t = threadIdx.x;
  const int tx = t & 15, ty = t >> 4;
  const size_t QSZ = (size_t)NB * NHD * SS * HD;
  const float* Qg = qkv;
  const float* Kg = qkv + QSZ;

  {
    int i0 = t, i1 = t + 256;
    linvs[i0 >> 6][i0 & 63] =
        linv[(size_t)(b * NHD + (i0 >> 6)) * SS + q0 + (i0 & 63)];
    linvs[i1 >> 6][i1 & 63] =
        linv[(size_t)(b * NHD + (i1 >> 6)) * SS + q0 + (i1 & 63)];
  }
  float pq[4][3];
#pragma unroll
  for (int i = 0; i < 4; ++i) {
    const float* pp = positions + ((size_t)b * SS + q0 + ty + 16 * i) * 3;
    pq[i][0] = pp[0]; pq[i][1] = pp[1]; pq[i][2] = pp[2];
  }
  const int sr = t >> 2, scol = (t & 3) * 16;

  for (int kti = 0; kti < 4; ++kti) {
    const int kt = ks * 256 + kti * 64;
    float d2m[4][4];
#pragma unroll
    for (int j = 0; j < 4; ++j) {
      int kk = kt + tx + 16 * j;
      const float* pp = positions + ((size_t)b * SS + kk) * 3;
      float px = pp[0], py = pp[1], pz = pp[2];
      int mval = amask[(size_t)b * SS + kk];
#pragma unroll
      for (int i = 0; i < 4; ++i) {
        float dx = pq[i][0] - px, dy = pq[i][1] - py, dz = pq[i][2] - pz;
        float d2 = dx * dx + dy * dy + dz * dz;
        d2m[i][j] = mval ? d2 : 3.0e8f;
      }
    }
    float am[4][4] = {};

    for (int h = 0; h < NHD; ++h) {
      __syncthreads();
      {
        const float* qp =
            Qg + ((size_t)(b * NHD + h) * SS + q0 + sr) * HD + scol;
        const float* kp =
            Kg + ((size_t)(b * NHD + h) * SS + kt + sr) * HD + scol;
#pragma unroll
        for (int u = 0; u < 4; ++u) {
          *(float4*)&Qs[sr][scol + 4 * u] = *(const float4*)(qp + 4 * u);
          *(float4*)&Ks[sr][scol + 4 * u] = *(const float4*)(kp + 4 * u);
        }
      }
      __syncthreads();

      float sc[4][4] = {};
#pragma unroll 2
      for (int d = 0; d < 64; d += 4) {
        float4 qa[4], kv[4];
#pragma unroll
        for (int i = 0; i < 4; ++i)
          qa[i] = *(const float4*)&Qs[ty + 16 * i][d];
#pragma unroll
        for (int j = 0; j < 4; ++j)
          kv[j] = *(const float4*)&Ks[tx + 16 * j][d];
#pragma unroll
        for (int i = 0; i < 4; ++i)
#pragma unroll
          for (int j = 0; j < 4; ++j)
            sc[i][j] += qa[i].x * kv[j].x + qa[i].y * kv[j].y +
                        qa[i].z * kv[j].z + qa[i].w * kv[j].w;
      }
#pragma unroll
      for (int i = 0; i < 4; ++i) {
        float li = linvs[h][ty + 16 * i];
#pragma unroll
        for (int j = 0; j < 4; ++j)
          am[i][j] +=
              __expf((sc[i][j] - d2m[i][j]) * 0.125f - CSHIFT) * li;
      }
    }  // h

#pragma unroll
    for (int i = 0; i < 4; ++i)
#pragma unroll
      for (int j = 0; j < 4; ++j)
        mean_out[((size_t)b * SS + q0 + ty + 16 * i) * SS + kt + tx +
                 16 * j] = am[i][j] * 0.125f;
  }  // kti
}

// ---------------------------------------------------------------------------
extern "C" void kernel_launch(void* const* d_in, const int* in_sizes, int n_in,
                              void* d_out, int out_size, void* d_ws,
                              size_t ws_size, hipStream_t stream) {
  const float* x         = (const float*)d_in[0];
  const float* positions = (const float*)d_in[1];
  const int*   amask     = (const int*)d_in[2];
  const float* w_qkv     = (const float*)d_in[3];
  const float* b_qkv     = (const float*)d_in[4];
  const float* w_out     = (const float*)d_in[5];
  const float* b_out     = (const float*)d_in[6];

  float* out      = (float*)d_out;                // [B,S,H]
  float* mean_out = out + (size_t)NB * SS * HH;   // [B,S,S]

  // ws (floats): qkv[3][B][NH][S][HD] | linv[B*NH*S] | ao[B,S,H] = 64.25 MB
  float* ws   = (float*)d_ws;
  const size_t QSZ = (size_t)NB * NHD * SS * HD;  // 4,194,304
  float* qkv  = ws;
  float* linv = ws + 3 * QSZ;
  float* ao   = linv + (size_t)NB * NHD * SS;

  dim3 blk(256);
  gemm_kernel<<<dim3(128, 24), blk, 0, stream>>>(x, w_qkv, b_qkv, qkv, 0);
  attn_o_kernel<<<dim3(64, NB, NHD), blk, 0, stream>>>(qkv, positions, amask,
                                                       ao, linv);
  mean_kernel<<<dim3(32, NB, 8), blk, 0, stream>>>(qkv, positions, amask,
                                                   linv, mean_out);
  gemm_kernel<<<dim3(128, 8), blk, 0, stream>>>(ao, w_out, b_out, out, 1);
}

// Round 4
// 740.993 us; speedup vs baseline: 21.9771x; 1.8984x over previous
//
#include <hip/hip_runtime.h>
#include <math.h>

#define NB 4
#define SS 2048
#define HH 512
#define NHD 8
#define HD 64
#define CSHIFT 24.0f   // fixed softmax shift: exact (|scores| < ~20), no max pass

typedef __attribute__((ext_vector_type(8))) short short8;   // 8 bf16 = 4 VGPR
typedef __attribute__((ext_vector_type(4))) float floatx4;  // MFMA C/D

__device__ __forceinline__ floatx4 mfma16(short8 a, short8 b, floatx4 c) {
  return __builtin_amdgcn_mfma_f32_16x16x32_bf16(a, b, c, 0, 0, 0);
}

__device__ __forceinline__ unsigned short bf16_rne(float f) {
  unsigned v = __float_as_uint(f);
  v += 0x7fffu + ((v >> 16) & 1u);
  return (unsigned short)(v >> 16);
}

// x = hi (truncated bf16) + lo (RNE bf16 of remainder): ~2^-17 relative total
__device__ __forceinline__ void split_bf16(float f, unsigned short& hi,
                                           unsigned short& lo) {
  unsigned u = __float_as_uint(f);
  hi = (unsigned short)(u >> 16);
  float rem = f - __uint_as_float(u & 0xffff0000u);
  lo = bf16_rne(rem);
}

// ---------------------------------------------------------------------------
// Stage a 64x64 bf16 tile (row-major, rowStride ushorts) into frag-linear LDS:
// dst[nt(=r>>4)][ks(=c>>5)][lane' = (r&15)+16*((c>>3)&3)][8 bf16].
// This is simultaneously the A-frag and B-frag layout for 16x16x32
// (lane = (row%16) + 16*quad, element k = quad*8+j). 256 threads.
// ---------------------------------------------------------------------------
__device__ __forceinline__ void stage_frag64(short* dstHi, short* dstLo,
                                             const unsigned short* srcHi,
                                             const unsigned short* srcLo,
                                             int t, int rowStride) {
  const int r = t >> 2, cg = t & 3;
  const size_t so = (size_t)r * rowStride + cg * 16;
  uint4 h0 = *(const uint4*)(srcHi + so);
  uint4 h1 = *(const uint4*)(srcHi + so + 8);
  uint4 l0 = *(const uint4*)(srcLo + so);
  uint4 l1 = *(const uint4*)(srcLo + so + 8);
  const int nt = r >> 4, rr = r & 15;
  const int c0 = cg * 16, c1 = c0 + 8;
  const int i0 = ((nt * 2 + (c0 >> 5)) * 64 + rr + 16 * ((c0 >> 3) & 3)) * 8;
  const int i1 = ((nt * 2 + (c1 >> 5)) * 64 + rr + 16 * ((c1 >> 3) & 3)) * 8;
  *(uint4*)&dstHi[i0] = h0;
  *(uint4*)&dstHi[i1] = h1;
  *(uint4*)&dstLo[i0] = l0;
  *(uint4*)&dstLo[i1] = l1;
}

// ---------------------------------------------------------------------------
// GEMM (r1-proven core): out = A @ W^T + bias. Tile 64x64, BK=32, 4x4 micro.
// mode 0: N=1536 -> split-bf16 epilogue:
//   Qhi/Qlo, Khi/Klo row-major [b][h][s][64]; Vthi/Vtlo TRANSPOSED [b][h][d][s]
// mode 1: plain fp32 [M x 512].
// ---------------------------------------------------------------------------
__global__ __launch_bounds__(256) void gemm_kernel(
    const float* __restrict__ A, const float* __restrict__ W,
    const float* __restrict__ bias, float* __restrict__ out, int mode) {
  __shared__ __align__(16) float As[64][36];
  __shared__ __align__(16) float Bs[64][36];
  const int t = threadIdx.x;
  const int m0 = blockIdx.x * 64;
  const int n0 = blockIdx.y * 64;
  const int tx = t & 15, ty = t >> 4;
  const int lr = t >> 2;
  const int lc = (t & 3) * 8;

  float acc[4][4] = {};
  for (int k0 = 0; k0 < 512; k0 += 32) {
    const float* ap = A + (size_t)(m0 + lr) * 512 + k0 + lc;
    float4 a0 = *(const float4*)ap;
    float4 a1 = *(const float4*)(ap + 4);
    const float* wp = W + (size_t)(n0 + lr) * 512 + k0 + lc;
    float4 b0 = *(const float4*)wp;
    float4 b1 = *(const float4*)(wp + 4);
    __syncthreads();
    *(float4*)&As[lr][lc]     = a0;
    *(float4*)&As[lr][lc + 4] = a1;
    *(float4*)&Bs[lr][lc]     = b0;
    *(float4*)&Bs[lr][lc + 4] = b1;
    __syncthreads();
#pragma unroll 2
    for (int kk = 0; kk < 32; kk += 4) {
      float4 av[4], bv[4];
#pragma unroll
      for (int i = 0; i < 4; ++i) av[i] = *(const float4*)&As[ty * 4 + i][kk];
#pragma unroll
      for (int j = 0; j < 4; ++j) bv[j] = *(const float4*)&Bs[tx * 4 + j][kk];
#pragma unroll
      for (int i = 0; i < 4; ++i)
#pragma unroll
        for (int j = 0; j < 4; ++j)
          acc[i][j] += av[i].x * bv[j].x + av[i].y * bv[j].y +
                       av[i].z * bv[j].z + av[i].w * bv[j].w;
    }
  }

  float4 bb = *(const float4*)&bias[n0 + tx * 4];
  float bbv[4] = {bb.x, bb.y, bb.z, bb.w};
  if (mode == 0) {
    const size_t QE = (size_t)NB * NHD * SS * HD;
    const int which = n0 >> 9;
    const int h = (n0 & 511) >> 6;
    const int b = m0 >> 11;
    const int srow = m0 & 2047;
    unsigned short* o16 = (unsigned short*)out;
    if (which < 2) {  // Q or K: row-major bf16 hi/lo
      unsigned short* dhi = o16 + (size_t)which * 2 * QE;
      unsigned short* dlo = dhi + QE;
#pragma unroll
      for (int i = 0; i < 4; ++i) {
        size_t idx =
            (((size_t)(b * NHD + h)) * SS + srow + ty * 4 + i) * HD + tx * 4;
        unsigned short hs[4], ls[4];
#pragma unroll
        for (int j = 0; j < 4; ++j)
          split_bf16(acc[i][j] + bbv[j], hs[j], ls[j]);
        *(uint2*)&dhi[idx] = make_uint2(
            (unsigned)hs[0] | ((unsigned)hs[1] << 16),
            (unsigned)hs[2] | ((unsigned)hs[3] << 16));
        *(uint2*)&dlo[idx] = make_uint2(
            (unsigned)ls[0] | ((unsigned)ls[1] << 16),
            (unsigned)ls[2] | ((unsigned)ls[3] << 16));
      }
    } else {  // V: transposed [b][h][d][s] bf16 hi/lo
      unsigned short* dhi = o16 + 4 * QE;
      unsigned short* dlo = dhi + QE;
#pragma unroll
      for (int j = 0; j < 4; ++j) {
        size_t idx =
            (((size_t)(b * NHD + h)) * HD + tx * 4 + j) * SS + srow + ty * 4;
        unsigned short hs[4], ls[4];
#pragma unroll
        for (int i = 0; i < 4; ++i)
          split_bf16(acc[i][j] + bbv[j], hs[i], ls[i]);
        *(uint2*)&dhi[idx] = make_uint2(
            (unsigned)hs[0] | ((unsigned)hs[1] << 16),
            (unsigned)hs[2] | ((unsigned)hs[3] << 16));
        *(uint2*)&dlo[idx] = make_uint2(
            (unsigned)ls[0] | ((unsigned)ls[1] << 16),
            (unsigned)ls[2] | ((unsigned)ls[3] << 16));
      }
    }
  } else {
#pragma unroll
    for (int i = 0; i < 4; ++i) {
      float4 r;
      r.x = acc[i][0] + bbv[0]; r.y = acc[i][1] + bbv[1];
      r.z = acc[i][2] + bbv[2]; r.w = acc[i][3] + bbv[3];
      *(float4*)&out[(size_t)(m0 + ty * 4 + i) * HH + n0 + tx * 4] = r;
    }
  }
}

// ---------------------------------------------------------------------------
// attn_o (MFMA): block = (q-tile 64, b, h). Computes S^T = K·Q^T per k-tile
// (3-pass split-bf16), p = exp((s-d2)/8 - C) in S^T C-layout (lane's 4 regs =
// 4 consecutive k at fixed q -> packed b64 write into P A-frag LDS), then
// O += P·V (2-pass: P bf16 single, V hi+lo). Unnormalized O + l; epilogue
// normalizes, writes ao fp32 [B,S,H] and linv.
// ---------------------------------------------------------------------------
__global__ __launch_bounds__(256) void attn_o_kernel(
    const unsigned short* __restrict__ o16, const float* __restrict__ positions,
    const int* __restrict__ amask, float* __restrict__ ao,
    float* __restrict__ linv) {
  const size_t QE = (size_t)NB * NHD * SS * HD;
  __shared__ short Qf[8192];   // [hl][ntq4][ks2][lane64][8]
  __shared__ short Kf[8192];
  __shared__ short Vf[8192];
  __shared__ short Pf[4096];   // [mtq4][ks2][lane64][8] (single bf16)
  __shared__ float4 posk[64];
  __shared__ float lred[128];
  __shared__ float linv_s[64];
  const int q0 = blockIdx.x * 64;
  const int b = blockIdx.y, h = blockIdx.z;
  const int t = threadIdx.x, w = t >> 6, lane = t & 63;
  const int quad = lane >> 4, l15 = lane & 15;
  const int mtk0 = (w & 1) * 2, ntq0 = (w >> 1) * 2;  // S^T tiles (k x q)
  const int mtq0 = (w & 1) * 2, ntd0 = (w >> 1) * 2;  // O tiles  (q x d)
  const unsigned short* qhi = o16;
  const unsigned short* qlo = o16 + QE;
  const unsigned short* khi = o16 + 2 * QE;
  const unsigned short* klo = o16 + 3 * QE;
  const unsigned short* vhi = o16 + 4 * QE;
  const unsigned short* vlo = o16 + 5 * QE;
  const size_t hb = (size_t)(b * NHD + h);

  stage_frag64(Qf, Qf + 4096, qhi + (hb * SS + q0) * HD,
               qlo + (hb * SS + q0) * HD, t, HD);

  float pqx[2], pqy[2], pqz[2];
#pragma unroll
  for (int ni = 0; ni < 2; ++ni) {
    int qg = q0 + (ntq0 + ni) * 16 + l15;
    const float* pp = positions + ((size_t)b * SS + qg) * 3;
    pqx[ni] = pp[0]; pqy[ni] = pp[1]; pqz[ni] = pp[2];
  }

  const floatx4 fz = {0.f, 0.f, 0.f, 0.f};
  floatx4 Ot[2][2] = {{fz, fz}, {fz, fz}};
  float lp0 = 0.f, lp1 = 0.f;

  for (int kt = 0; kt < SS; kt += 64) {
    __syncthreads();  // prior iter's Kf/Vf/Pf/posk reads complete
    stage_frag64(Kf, Kf + 4096, khi + (hb * SS + kt) * HD,
                 klo + (hb * SS + kt) * HD, t, HD);
    stage_frag64(Vf, Vf + 4096, vhi + hb * HD * SS + kt,
                 vlo + hb * HD * SS + kt, t, SS);
    if (t < 64) {
      int kk = kt + t;
      const float* pp = positions + ((size_t)b * SS + kk) * 3;
      float bump = amask[(size_t)b * SS + kk] ? 0.f : 1.0e4f;
      posk[t] = make_float4(pp[0] + bump, pp[1], pp[2], 0.f);
    }
    __syncthreads();

    // QK: S^T[k][q], 3-pass split-bf16
    floatx4 acc[2][2] = {{fz, fz}, {fz, fz}};
#pragma unroll
    for (int ks = 0; ks < 2; ++ks) {
      short8 ah[2], al[2], bh[2], bl[2];
#pragma unroll
      for (int mi = 0; mi < 2; ++mi) {
        int o = (((mtk0 + mi) * 2 + ks) * 64 + lane) * 8;
        ah[mi] = *(const short8*)&Kf[o];
        al[mi] = *(const short8*)&Kf[4096 + o];
      }
#pragma unroll
      for (int ni = 0; ni < 2; ++ni) {
        int o = (((ntq0 + ni) * 2 + ks) * 64 + lane) * 8;
        bh[ni] = *(const short8*)&Qf[o];
        bl[ni] = *(const short8*)&Qf[4096 + o];
      }
#pragma unroll
      for (int mi = 0; mi < 2; ++mi)
#pragma unroll
        for (int ni = 0; ni < 2; ++ni) {
          acc[mi][ni] = mfma16(ah[mi], bh[ni], acc[mi][ni]);
          acc[mi][ni] = mfma16(ah[mi], bl[ni], acc[mi][ni]);
          acc[mi][ni] = mfma16(al[mi], bh[ni], acc[mi][ni]);
        }
    }

    // exp + pack P (S^T C-layout: lane = (k-quad, q-col), regs = 4 consec k)
    unsigned pb[2][2][2];
#pragma unroll
    for (int mi = 0; mi < 2; ++mi) {
      unsigned short tmp[2][4];
#pragma unroll
      for (int r = 0; r < 4; ++r) {
        int kl = (mtk0 + mi) * 16 + quad * 4 + r;
        float4 pk = posk[kl];
#pragma unroll
        for (int ni = 0; ni < 2; ++ni) {
          float dx = pqx[ni] - pk.x, dy = pqy[ni] - pk.y, dz = pqz[ni] - pk.z;
          float d2 = dx * dx + dy * dy + dz * dz;
          float p = __expf((acc[mi][ni][r] - d2) * 0.125f - CSHIFT);
          if (ni == 0) lp0 += p; else lp1 += p;
          tmp[ni][r] = bf16_rne(p);
        }
      }
#pragma unroll
      for (int ni = 0; ni < 2; ++ni) {
        pb[mi][ni][0] = (unsigned)tmp[ni][0] | ((unsigned)tmp[ni][1] << 16);
        pb[mi][ni][1] = (unsigned)tmp[ni][2] | ((unsigned)tmp[ni][3] << 16);
      }
    }
#pragma unroll
    for (int mi = 0; mi < 2; ++mi) {
      int mk = mtk0 + mi;
#pragma unroll
      for (int ni = 0; ni < 2; ++ni) {
        int idx = (((ntq0 + ni) * 2 + (mk >> 1)) * 64 + l15 +
                   16 * ((mk & 1) * 2 + (quad >> 1))) * 8 + (quad & 1) * 4;
        *(uint2*)&Pf[idx] = make_uint2(pb[mi][ni][0], pb[mi][ni][1]);
      }
    }
    __syncthreads();  // Pf visible

    // PV: O[q][d] += P·(Vhi+Vlo)
#pragma unroll
    for (int ks = 0; ks < 2; ++ks) {
      short8 pa[2], vh[2], vl[2];
#pragma unroll
      for (int mi = 0; mi < 2; ++mi)
        pa[mi] = *(const short8*)&Pf[(((mtq0 + mi) * 2 + ks) * 64 + lane) * 8];
#pragma unroll
      for (int ni = 0; ni < 2; ++ni) {
        int o = (((ntd0 + ni) * 2 + ks) * 64 + lane) * 8;
        vh[ni] = *(const short8*)&Vf[o];
        vl[ni] = *(const short8*)&Vf[4096 + o];
      }
#pragma unroll
      for (int mi = 0; mi < 2; ++mi)
#pragma unroll
        for (int ni = 0; ni < 2; ++ni) {
          Ot[mi][ni] = mfma16(pa[mi], vh[ni], Ot[mi][ni]);
          Ot[mi][ni] = mfma16(pa[mi], vl[ni], Ot[mi][ni]);
        }
    }
  }  // kt

  // reduce l across quads (shfl) then across wave pairs (LDS)
  lp0 += __shfl_xor(lp0, 16); lp0 += __shfl_xor(lp0, 32);
  lp1 += __shfl_xor(lp1, 16); lp1 += __shfl_xor(lp1, 32);
  if (lane < 16) {
    lred[(w * 2 + 0) * 16 + l15] = lp0;
    lred[(w * 2 + 1) * 16 + l15] = lp1;
  }
  __syncthreads();
  if (t < 64) {
    int nq = t >> 4, qi = t & 15;
    int wA = (nq >> 1) * 2, ni = nq & 1;
    float l = lred[(wA * 2 + ni) * 16 + qi] + lred[((wA + 1) * 2 + ni) * 16 + qi];
    float li = 1.0f / fmaxf(l, 1e-30f);
    linv_s[t] = li;
    linv[hb * SS + q0 + t] = li;
  }
  __syncthreads();
#pragma unroll
  for (int mi = 0; mi < 2; ++mi)
#pragma unroll
    for (int ni = 0; ni < 2; ++ni)
#pragma unroll
      for (int r = 0; r < 4; ++r) {
        int ql = (mtq0 + mi) * 16 + quad * 4 + r;
        float li = linv_s[ql];
        ao[((size_t)b * SS + q0 + ql) * HH + h * HD + (ntd0 + ni) * 16 + l15] =
            Ot[mi][ni][r] * li;
      }
}

// ---------------------------------------------------------------------------
// mean (MFMA): block = (q-tile 64, b, k-chunk 256). h looped outside, 4
// k-tiles inside; am[4][2][2] fp32 regs accumulate normalized p over heads.
// Final: LDS transpose (S^T C-layout -> [q][k]) + coalesced float4 stores.
// ---------------------------------------------------------------------------
__global__ __launch_bounds__(256) void mean_kernel(
    const unsigned short* __restrict__ o16, const float* __restrict__ positions,
    const int* __restrict__ amask, const float* __restrict__ linv,
    float* __restrict__ mean_out) {
  const size_t QE = (size_t)NB * NHD * SS * HD;
  __shared__ short Qf[8192];
  __shared__ short Kf[8192];
  __shared__ float4 posk4[256];
  __shared__ float linvs[64];
  __shared__ __align__(16) float Pm[64 * 68];
  const int q0 = blockIdx.x * 64;
  const int b = blockIdx.y, kc = blockIdx.z;
  const int t = threadIdx.x, w = t >> 6, lane = t & 63;
  const int quad = lane >> 4, l15 = lane & 15;
  const int mtk0 = (w & 1) * 2, ntq0 = (w >> 1) * 2;
  const unsigned short* qhi = o16;
  const unsigned short* qlo = o16 + QE;
  const unsigned short* khi = o16 + 2 * QE;
  const unsigned short* klo = o16 + 3 * QE;

  {
    int kk = kc * 256 + t;
    const float* pp = positions + ((size_t)b * SS + kk) * 3;
    float bump = amask[(size_t)b * SS + kk] ? 0.f : 1.0e4f;
    posk4[t] = make_float4(pp[0] + bump, pp[1], pp[2], 0.f);
  }
  float pqx[2], pqy[2], pqz[2];
#pragma unroll
  for (int ni = 0; ni < 2; ++ni) {
    int qg = q0 + (ntq0 + ni) * 16 + l15;
    const float* pp = positions + ((size_t)b * SS + qg) * 3;
    pqx[ni] = pp[0]; pqy[ni] = pp[1]; pqz[ni] = pp[2];
  }

  const floatx4 fz = {0.f, 0.f, 0.f, 0.f};
  floatx4 am[4][2][2];
#pragma unroll
  for (int ki = 0; ki < 4; ++ki)
#pragma unroll
    for (int mi = 0; mi < 2; ++mi)
#pragma unroll
      for (int ni = 0; ni < 2; ++ni) am[ki][mi][ni] = fz;

  for (int h = 0; h < NHD; ++h) {
    const size_t hb = (size_t)(b * NHD + h);
    __syncthreads();  // prior h's Qf/linvs reads complete
    stage_frag64(Qf, Qf + 4096, qhi + (hb * SS + q0) * HD,
                 qlo + (hb * SS + q0) * HD, t, HD);
    if (t < 64) linvs[t] = linv[hb * SS + q0 + t];
    for (int ki = 0; ki < 4; ++ki) {
      const int kt = kc * 256 + ki * 64;
      __syncthreads();  // prior Kf reads complete (and Qf/linvs visible)
      stage_frag64(Kf, Kf + 4096, khi + (hb * SS + kt) * HD,
                   klo + (hb * SS + kt) * HD, t, HD);
      __syncthreads();

      floatx4 acc[2][2] = {{fz, fz}, {fz, fz}};
#pragma unroll
      for (int ks = 0; ks < 2; ++ks) {
        short8 ah[2], al[2], bh[2], bl[2];
#pragma unroll
        for (int mi = 0; mi < 2; ++mi) {
          int o = (((mtk0 + mi) * 2 + ks) * 64 + lane) * 8;
          ah[mi] = *(const short8*)&Kf[o];
          al[mi] = *(const short8*)&Kf[4096 + o];
        }
#pragma unroll
        for (int ni = 0; ni < 2; ++ni) {
          int o = (((ntq0 + ni) * 2 + ks) * 64 + lane) * 8;
          bh[ni] = *(const short8*)&Qf[o];
          bl[ni] = *(const short8*)&Qf[4096 + o];
        }
#pragma unroll
        for (int mi = 0; mi < 2; ++mi)
#pragma unroll
          for (int ni = 0; ni < 2; ++ni) {
            acc[mi][ni] = mfma16(ah[mi], bh[ni], acc[mi][ni]);
            acc[mi][ni] = mfma16(ah[mi], bl[ni], acc[mi][ni]);
            acc[mi][ni] = mfma16(al[mi], bh[ni], acc[mi][ni]);
          }
      }

      float li[2] = {linvs[(ntq0 + 0) * 16 + l15], linvs[(ntq0 + 1) * 16 + l15]};
#pragma unroll
      for (int mi = 0; mi < 2; ++mi)
#pragma unroll
        for (int r = 0; r < 4; ++r) {
          int kl = (mtk0 + mi) * 16 + quad * 4 + r;
          float4 pk = posk4[ki * 64 + kl];
#pragma unroll
          for (int ni = 0; ni < 2; ++ni) {
            float dx = pqx[ni] - pk.x, dy = pqy[ni] - pk.y,
                  dz = pqz[ni] - pk.z;
            float d2 = dx * dx + dy * dy + dz * dz;
            am[ki][mi][ni][r] +=
                __expf((acc[mi][ni][r] - d2) * 0.125f - CSHIFT) * li[ni];
          }
        }
    }  // ki
  }  // h

  // transpose + store each k-tile
  for (int ki = 0; ki < 4; ++ki) {
    const int kt = kc * 256 + ki * 64;
    __syncthreads();  // Pm reuse safe
#pragma unroll
    for (int mi = 0; mi < 2; ++mi)
#pragma unroll
      for (int ni = 0; ni < 2; ++ni) {
        int q = (ntq0 + ni) * 16 + l15;
        int k0 = (mtk0 + mi) * 16 + quad * 4;
        *(float4*)&Pm[q * 68 + k0] =
            make_float4(am[ki][mi][ni][0], am[ki][mi][ni][1],
                        am[ki][mi][ni][2], am[ki][mi][ni][3]);
      }
    __syncthreads();
    {
      int q = t >> 2, c0 = (t & 3) * 16;
#pragma unroll
      for (int u = 0; u < 4; ++u) {
        float4 v = *(const float4*)&Pm[q * 68 + c0 + u * 4];
        v.x *= 0.125f; v.y *= 0.125f; v.z *= 0.125f; v.w *= 0.125f;
        *(float4*)&mean_out[((size_t)b * SS + q0 + q) * SS + kt + c0 + u * 4] =
            v;
      }
    }
  }
}

// ---------------------------------------------------------------------------
extern "C" void kernel_launch(void* const* d_in, const int* in_sizes, int n_in,
                              void* d_out, int out_size, void* d_ws,
                              size_t ws_size, hipStream_t stream) {
  const float* x         = (const float*)d_in[0];
  const float* positions = (const float*)d_in[1];
  const int*   amask     = (const int*)d_in[2];
  const float* w_qkv     = (const float*)d_in[3];
  const float* b_qkv     = (const float*)d_in[4];
  const float* w_out     = (const float*)d_in[5];
  const float* b_out     = (const float*)d_in[6];

  float* out      = (float*)d_out;                // [B,S,H]
  float* mean_out = out + (size_t)NB * SS * HH;   // [B,S,S]

  // ws: 6 bf16 arrays (Qhi,Qlo,Khi,Klo,Vthi,Vtlo) | linv f32 | ao f32 = 67.4MB
  const size_t QE = (size_t)NB * NHD * SS * HD;   // 4,194,304 elements
  unsigned short* o16 = (unsigned short*)d_ws;
  float* linv = (float*)(o16 + 6 * QE);
  float* ao   = linv + (size_t)NB * NHD * SS;

  dim3 blk(256);
  gemm_kernel<<<dim3(128, 24), blk, 0, stream>>>(x, w_qkv, b_qkv, (float*)o16,
                                                 0);
  attn_o_kernel<<<dim3(32, NB, NHD), blk, 0, stream>>>(o16, positions, amask,
                                                       ao, linv);
  mean_kernel<<<dim3(32, NB, 8), blk, 0, stream>>>(o16, positions, amask, linv,
                                                   mean_out);
  gemm_kernel<<<dim3(128, 8), blk, 0, stream>>>(ao, w_out, b_out, out, 1);
}

// Round 5
// 703.725 us; speedup vs baseline: 23.1410x; 1.0530x over previous
//
#include <hip/hip_runtime.h>
#include <math.h>

#define NB 4
#define SS 2048
#define HH 512
#define NHD 8
#define HD 64
#define CSHIFT 24.0f   // fixed softmax shift: exact (|scores| < ~20), no max pass

typedef __attribute__((ext_vector_type(8))) short short8;   // 8 bf16 = 4 VGPR
typedef __attribute__((ext_vector_type(4))) float floatx4;  // MFMA C/D

__device__ __forceinline__ floatx4 mfma16(short8 a, short8 b, floatx4 c) {
  return __builtin_amdgcn_mfma_f32_16x16x32_bf16(a, b, c, 0, 0, 0);
}

__device__ __forceinline__ unsigned short bf16_rne(float f) {
  unsigned v = __float_as_uint(f);
  v += 0x7fffu + ((v >> 16) & 1u);
  return (unsigned short)(v >> 16);
}

// x = hi (truncated bf16) + lo (RNE bf16 of remainder): ~2^-17 relative total
__device__ __forceinline__ void split_bf16(float f, unsigned short& hi,
                                           unsigned short& lo) {
  unsigned u = __float_as_uint(f);
  hi = (unsigned short)(u >> 16);
  float rem = f - __uint_as_float(u & 0xffff0000u);
  lo = bf16_rne(rem);
}

// ---------------------------------------------------------------------------
// split fp32 array -> bf16 hi/lo arrays (vectorized, n4 = n/4)
// ---------------------------------------------------------------------------
__global__ __launch_bounds__(256) void split_kernel(
    const float* __restrict__ src, unsigned short* __restrict__ dhi,
    unsigned short* __restrict__ dlo, int n4) {
  int i = blockIdx.x * 256 + threadIdx.x;
  if (i >= n4) return;
  float4 v = ((const float4*)src)[i];
  unsigned short h[4], l[4];
  split_bf16(v.x, h[0], l[0]);
  split_bf16(v.y, h[1], l[1]);
  split_bf16(v.z, h[2], l[2]);
  split_bf16(v.w, h[3], l[3]);
  *(uint2*)&dhi[(size_t)i * 4] =
      make_uint2((unsigned)h[0] | ((unsigned)h[1] << 16),
                 (unsigned)h[2] | ((unsigned)h[3] << 16));
  *(uint2*)&dlo[(size_t)i * 4] =
      make_uint2((unsigned)l[0] | ((unsigned)l[1] << 16),
                 (unsigned)l[2] | ((unsigned)l[3] << 16));
}

// ---------------------------------------------------------------------------
// Shared MFMA-GEMM core: C(128x128 block, 64x64/wave, 4x4 16-tiles) =
// (Ah+Al)(Bh+Bl)^T over K=512, 3-pass (drops lo*lo). A,B row-major bf16,
// stride 512, pre-offset to the wave's 64-row origins. All operand frags are
// contiguous 16B global loads (lane row = l15, k = quad*8+j) -> NO LDS.
// ---------------------------------------------------------------------------
__device__ __forceinline__ void mm_core(const unsigned short* __restrict__ Ah,
                                        const unsigned short* __restrict__ Al,
                                        const unsigned short* __restrict__ Bh,
                                        const unsigned short* __restrict__ Bl,
                                        int lane, floatx4 acc[4][4]) {
  const int quad = lane >> 4, l15 = lane & 15;
  const int ko = quad * 8;
#pragma unroll 1
  for (int k0 = 0; k0 < 512; k0 += 32) {
    short8 ah[4], al[4], bh[4], bl[4];
#pragma unroll
    for (int mt = 0; mt < 4; ++mt) {
      size_t o = (size_t)(mt * 16 + l15) * 512 + k0 + ko;
      ah[mt] = *(const short8*)(Ah + o);
      al[mt] = *(const short8*)(Al + o);
      bh[mt] = *(const short8*)(Bh + o);
      bl[mt] = *(const short8*)(Bl + o);
    }
#pragma unroll
    for (int mt = 0; mt < 4; ++mt)
#pragma unroll
      for (int nt = 0; nt < 4; ++nt) {
        acc[mt][nt] = mfma16(ah[mt], bh[nt], acc[mt][nt]);
        acc[mt][nt] = mfma16(ah[mt], bl[nt], acc[mt][nt]);
        acc[mt][nt] = mfma16(al[mt], bh[nt], acc[mt][nt]);
      }
  }
}

// ---------------------------------------------------------------------------
// GEMM1a: Q,K transposed-orientation: C[m = w_qkv row 0..1023][n = s].
// C-layout rows (quad*4+r) = 4 consecutive d -> packed uint2 bf16 hi/lo
// stores into Qhi/Qlo/Khi/Klo [b][h][s][d].
// ---------------------------------------------------------------------------
__global__ __launch_bounds__(256) void qk_gemm_kernel(
    const unsigned short* __restrict__ wqh, const unsigned short* __restrict__ wql,
    const unsigned short* __restrict__ xhi, const unsigned short* __restrict__ xlo,
    const float* __restrict__ b_qkv, unsigned short* __restrict__ qhi,
    unsigned short* __restrict__ qlo, unsigned short* __restrict__ khi,
    unsigned short* __restrict__ klo) {
  const int t = threadIdx.x, w = t >> 6, lane = t & 63;
  const int quad = lane >> 4, l15 = lane & 15;
  const int m0 = blockIdx.x * 128 + (w & 1) * 64;   // w_qkv row origin
  const int n0 = blockIdx.y * 128 + (w >> 1) * 64;  // s origin
  const floatx4 fz = {0.f, 0.f, 0.f, 0.f};
  floatx4 acc[4][4];
#pragma unroll
  for (int i = 0; i < 4; ++i)
#pragma unroll
    for (int j = 0; j < 4; ++j) acc[i][j] = fz;
  mm_core(wqh + (size_t)m0 * 512, wql + (size_t)m0 * 512,
          xhi + (size_t)n0 * 512, xlo + (size_t)n0 * 512, lane, acc);
#pragma unroll
  for (int mt = 0; mt < 4; ++mt) {
    const int mb = m0 + mt * 16 + quad * 4;  // w-row base, 4-aligned
    float4 b4 = *(const float4*)&b_qkv[mb];
    float bv[4] = {b4.x, b4.y, b4.z, b4.w};
    const int which = mb >> 9, h = (mb >> 6) & 7, d0 = mb & 63;
    unsigned short* dhi = which ? khi : qhi;
    unsigned short* dlo = which ? klo : qlo;
#pragma unroll
    for (int nt = 0; nt < 4; ++nt) {
      const int n = n0 + nt * 16 + l15;  // global s
      const int b = n >> 11, srow = n & 2047;
      unsigned short hs[4], ls[4];
#pragma unroll
      for (int r = 0; r < 4; ++r)
        split_bf16(acc[mt][nt][r] + bv[r], hs[r], ls[r]);
      size_t idx = (((size_t)(b * NHD + h)) * SS + srow) * HD + d0;
      *(uint2*)&dhi[idx] = make_uint2((unsigned)hs[0] | ((unsigned)hs[1] << 16),
                                      (unsigned)hs[2] | ((unsigned)hs[3] << 16));
      *(uint2*)&dlo[idx] = make_uint2((unsigned)ls[0] | ((unsigned)ls[1] << 16),
                                      (unsigned)ls[2] | ((unsigned)ls[3] << 16));
    }
  }
}

// ---------------------------------------------------------------------------
// GEMM1b: V normal orientation: C[m = s][n = V col 0..511]. C rows = 4
// consecutive s -> packed uint2 RNE-bf16 stores into transposed Vhi[b][h][d][s].
// ---------------------------------------------------------------------------
__global__ __launch_bounds__(256) void v_gemm_kernel(
    const unsigned short* __restrict__ xhi, const unsigned short* __restrict__ xlo,
    const unsigned short* __restrict__ wvh, const unsigned short* __restrict__ wvl,
    const float* __restrict__ b_qkv, unsigned short* __restrict__ vhi) {
  const int t = threadIdx.x, w = t >> 6, lane = t & 63;
  const int quad = lane >> 4, l15 = lane & 15;
  const int m0 = blockIdx.y * 128 + (w & 1) * 64;   // s origin
  const int n0 = blockIdx.x * 128 + (w >> 1) * 64;  // V col origin
  const floatx4 fz = {0.f, 0.f, 0.f, 0.f};
  floatx4 acc[4][4];
#pragma unroll
  for (int i = 0; i < 4; ++i)
#pragma unroll
    for (int j = 0; j < 4; ++j) acc[i][j] = fz;
  mm_core(xhi + (size_t)m0 * 512, xlo + (size_t)m0 * 512,
          wvh + (size_t)n0 * 512, wvl + (size_t)n0 * 512, lane, acc);
#pragma unroll
  for (int nt = 0; nt < 4; ++nt) {
    const int n = n0 + nt * 16 + l15;  // V col
    const int h = n >> 6, d = n & 63;
    const float bias = b_qkv[1024 + n];
#pragma unroll
    for (int mt = 0; mt < 4; ++mt) {
      const int mb = m0 + mt * 16 + quad * 4;  // s base, 4-aligned
      const int b = mb >> 11, srow = mb & 2047;
      unsigned short hs[4];
#pragma unroll
      for (int r = 0; r < 4; ++r) hs[r] = bf16_rne(acc[mt][nt][r] + bias);
      size_t idx = (((size_t)(b * NHD + h)) * HD + d) * SS + srow;
      *(uint2*)&vhi[idx] = make_uint2((unsigned)hs[0] | ((unsigned)hs[1] << 16),
                                      (unsigned)hs[2] | ((unsigned)hs[3] << 16));
    }
  }
}

// ---------------------------------------------------------------------------
// GEMM2: out = ao @ w_out^T + b_out, fp32 stores [B,S,H].
// ---------------------------------------------------------------------------
__global__ __launch_bounds__(256) void out_gemm_kernel(
    const unsigned short* __restrict__ aohi, const unsigned short* __restrict__ aolo,
    const unsigned short* __restrict__ woh, const unsigned short* __restrict__ wol,
    const float* __restrict__ b_out, float* __restrict__ out) {
  const int t = threadIdx.x, w = t >> 6, lane = t & 63;
  const int quad = lane >> 4, l15 = lane & 15;
  const int m0 = blockIdx.y * 128 + (w & 1) * 64;   // s origin
  const int n0 = blockIdx.x * 128 + (w >> 1) * 64;  // out col origin
  const floatx4 fz = {0.f, 0.f, 0.f, 0.f};
  floatx4 acc[4][4];
#pragma unroll
  for (int i = 0; i < 4; ++i)
#pragma unroll
    for (int j = 0; j < 4; ++j) acc[i][j] = fz;
  mm_core(aohi + (size_t)m0 * 512, aolo + (size_t)m0 * 512,
          woh + (size_t)n0 * 512, wol + (size_t)n0 * 512, lane, acc);
#pragma unroll
  for (int nt = 0; nt < 4; ++nt) {
    const int n = n0 + nt * 16 + l15;
    const float bias = b_out[n];
#pragma unroll
    for (int mt = 0; mt < 4; ++mt) {
      const int mb = m0 + mt * 16 + quad * 4;
#pragma unroll
      for (int r = 0; r < 4; ++r)
        out[(size_t)(mb + r) * HH + n] = acc[mt][nt][r] + bias;
    }
  }
}

// ---------------------------------------------------------------------------
// attn_o: block (q64, b, h). All MFMA operands direct-from-global (Q frags
// hoisted to regs for the whole kt loop). LDS only: positions table (once)
// + P quad-exchange (r4-verified indexing). V single-bf16 -> 1-pass PV.
// Unnormalized O + l; epilogue normalizes, writes ao bf16 hi/lo + linv.
// ---------------------------------------------------------------------------
__global__ __launch_bounds__(256) void attn_o_kernel(
    const unsigned short* __restrict__ qhi, const unsigned short* __restrict__ qlo,
    const unsigned short* __restrict__ khi, const unsigned short* __restrict__ klo,
    const unsigned short* __restrict__ vhi, const float* __restrict__ positions,
    const int* __restrict__ amask, unsigned short* __restrict__ aohi,
    unsigned short* __restrict__ aolo, float* __restrict__ linv) {
  __shared__ short Pf[4096];               // 8 KB: P A-frag exchange
  __shared__ __align__(16) float4 posk[SS];  // 32 KB: mask-folded positions
  __shared__ float lred[128];
  __shared__ float linv_s[64];
  const int q0 = blockIdx.x * 64;
  const int b = blockIdx.y, h = blockIdx.z;
  const int t = threadIdx.x, w = t >> 6, lane = t & 63;
  const int quad = lane >> 4, l15 = lane & 15;
  const int mtk0 = (w & 1) * 2, ntq0 = (w >> 1) * 2;  // S^T tiles (k x q)
  const int mtq0 = (w & 1) * 2, ntd0 = (w >> 1) * 2;  // O tiles  (q x d)
  const size_t hb = (size_t)(b * NHD + h);

#pragma unroll
  for (int u = 0; u < 8; ++u) {  // fold mask into k positions, once
    int kk = u * 256 + t;
    const float* pp = positions + ((size_t)b * SS + kk) * 3;
    float bump = amask[(size_t)b * SS + kk] ? 0.f : 1.0e4f;
    posk[kk] = make_float4(pp[0] + bump, pp[1], pp[2], 0.f);
  }

  // hoist Q frags (kt-invariant): 8 short8 = 32 VGPRs
  short8 qfh[2][2], qfl[2][2];
#pragma unroll
  for (int ni = 0; ni < 2; ++ni)
#pragma unroll
    for (int ks = 0; ks < 2; ++ks) {
      size_t o = (hb * SS + q0 + (ntq0 + ni) * 16 + l15) * HD + ks * 32 + quad * 8;
      qfh[ni][ks] = *(const short8*)(qhi + o);
      qfl[ni][ks] = *(const short8*)(qlo + o);
    }
  float pqx[2], pqy[2], pqz[2];
#pragma unroll
  for (int ni = 0; ni < 2; ++ni) {
    const float* pp = positions + ((size_t)b * SS + q0 + (ntq0 + ni) * 16 + l15) * 3;
    pqx[ni] = pp[0]; pqy[ni] = pp[1]; pqz[ni] = pp[2];
  }
  __syncthreads();  // posk visible

  const floatx4 fz = {0.f, 0.f, 0.f, 0.f};
  floatx4 Ot[2][2] = {{fz, fz}, {fz, fz}};
  float lp0 = 0.f, lp1 = 0.f;

#pragma unroll 1
  for (int kt = 0; kt < SS; kt += 64) {
    // issue K + V frag loads (direct global, contiguous 16B per lane)
    short8 kfh[2][2], kfl[2][2], vf[2][2];
#pragma unroll
    for (int mi = 0; mi < 2; ++mi)
#pragma unroll
      for (int ks = 0; ks < 2; ++ks) {
        size_t o = (hb * SS + kt + (mtk0 + mi) * 16 + l15) * HD + ks * 32 + quad * 8;
        kfh[mi][ks] = *(const short8*)(khi + o);
        kfl[mi][ks] = *(const short8*)(klo + o);
      }
#pragma unroll
    for (int ni = 0; ni < 2; ++ni)
#pragma unroll
      for (int ks = 0; ks < 2; ++ks) {
        size_t o = (hb * HD + (ntd0 + ni) * 16 + l15) * SS + kt + ks * 32 + quad * 8;
        vf[ni][ks] = *(const short8*)(vhi + o);
      }

    // QK: S^T = K·Q^T, 3-pass split-bf16
    floatx4 acc[2][2] = {{fz, fz}, {fz, fz}};
#pragma unroll
    for (int ks = 0; ks < 2; ++ks)
#pragma unroll
      for (int mi = 0; mi < 2; ++mi)
#pragma unroll
        for (int ni = 0; ni < 2; ++ni) {
          acc[mi][ni] = mfma16(kfh[mi][ks], qfh[ni][ks], acc[mi][ni]);
          acc[mi][ni] = mfma16(kfh[mi][ks], qfl[ni][ks], acc[mi][ni]);
          acc[mi][ni] = mfma16(kfl[mi][ks], qfh[ni][ks], acc[mi][ni]);
        }

    // exp + pack P (S^T C-layout -> A-frag LDS; r4-verified indexing)
    unsigned pb[2][2][2];
#pragma unroll
    for (int mi = 0; mi < 2; ++mi) {
      unsigned short tmp[2][4];
#pragma unroll
      for (int r = 0; r < 4; ++r) {
        int kl = (mtk0 + mi) * 16 + quad * 4 + r;
        float4 pk = posk[kt + kl];
#pragma unroll
        for (int ni = 0; ni < 2; ++ni) {
          float dx = pqx[ni] - pk.x, dy = pqy[ni] - pk.y, dz = pqz[ni] - pk.z;
          float d2 = dx * dx + dy * dy + dz * dz;
          float p = __expf((acc[mi][ni][r] - d2) * 0.125f - CSHIFT);
          if (ni == 0) lp0 += p; else lp1 += p;
          tmp[ni][r] = bf16_rne(p);
        }
      }
#pragma unroll
      for (int ni = 0; ni < 2; ++ni) {
        pb[mi][ni][0] = (unsigned)tmp[ni][0] | ((unsigned)tmp[ni][1] << 16);
        pb[mi][ni][1] = (unsigned)tmp[ni][2] | ((unsigned)tmp[ni][3] << 16);
      }
    }
    __syncthreads();  // prior PV reads of Pf complete
#pragma unroll
    for (int mi = 0; mi < 2; ++mi) {
      int mk = mtk0 + mi;
#pragma unroll
      for (int ni = 0; ni < 2; ++ni) {
        int idx = (((ntq0 + ni) * 2 + (mk >> 1)) * 64 + l15 +
                   16 * ((mk & 1) * 2 + (quad >> 1))) * 8 + (quad & 1) * 4;
        *(uint2*)&Pf[idx] = make_uint2(pb[mi][ni][0], pb[mi][ni][1]);
      }
    }
    __syncthreads();  // Pf visible

    // PV: O += P·V (single-pass, V RNE bf16)
#pragma unroll
    for (int ks = 0; ks < 2; ++ks) {
      short8 pa[2];
#pragma unroll
      for (int mi = 0; mi < 2; ++mi)
        pa[mi] = *(const short8*)&Pf[(((mtq0 + mi) * 2 + ks) * 64 + lane) * 8];
#pragma unroll
      for (int mi = 0; mi < 2; ++mi)
#pragma unroll
        for (int ni = 0; ni < 2; ++ni)
          Ot[mi][ni] = mfma16(pa[mi], vf[ni][ks], Ot[mi][ni]);
    }
  }  // kt

  // reduce l across quads (shfl) then across wave pairs (LDS) — r4-verified
  lp0 += __shfl_xor(lp0, 16); lp0 += __shfl_xor(lp0, 32);
  lp1 += __shfl_xor(lp1, 16); lp1 += __shfl_xor(lp1, 32);
  if (lane < 16) {
    lred[(w * 2 + 0) * 16 + l15] = lp0;
    lred[(w * 2 + 1) * 16 + l15] = lp1;
  }
  __syncthreads();
  if (t < 64) {
    int nq = t >> 4, qi = t & 15;
    int wA = (nq >> 1) * 2, ni = nq & 1;
    float l = lred[(wA * 2 + ni) * 16 + qi] + lred[((wA + 1) * 2 + ni) * 16 + qi];
    float li = 1.0f / fmaxf(l, 1e-30f);
    linv_s[t] = li;
    linv[hb * SS + q0 + t] = li;
  }
  __syncthreads();
#pragma unroll
  for (int mi = 0; mi < 2; ++mi)
#pragma unroll
    for (int ni = 0; ni < 2; ++ni)
#pragma unroll
      for (int r = 0; r < 4; ++r) {
        int ql = (mtq0 + mi) * 16 + quad * 4 + r;
        float ov = Ot[mi][ni][r] * linv_s[ql];
        unsigned short hv, lv;
        split_bf16(ov, hv, lv);
        size_t idx =
            ((size_t)b * SS + q0 + ql) * HH + h * HD + (ntd0 + ni) * 16 + l15;
        aohi[idx] = hv;
        aolo[idx] = lv;
      }
}

// ---------------------------------------------------------------------------
// mean: block (q64, b, k-chunk 256). ki OUTER (d2 hoisted out of h), h inner
// with zero barriers (operands direct-global). Per ki: transpose via Pm +
// coalesced float4 stores.
// ---------------------------------------------------------------------------
__global__ __launch_bounds__(256) void mean_kernel(
    const unsigned short* __restrict__ qhi, const unsigned short* __restrict__ qlo,
    const unsigned short* __restrict__ khi, const unsigned short* __restrict__ klo,
    const float* __restrict__ positions, const int* __restrict__ amask,
    const float* __restrict__ linv, float* __restrict__ mean_out) {
  __shared__ __align__(16) float4 posk4[256];
  __shared__ __align__(16) float Pm[64 * 68];
  const int q0 = blockIdx.x * 64;
  const int b = blockIdx.y, kc = blockIdx.z;
  const int t = threadIdx.x, w = t >> 6, lane = t & 63;
  const int quad = lane >> 4, l15 = lane & 15;
  const int mtk0 = (w & 1) * 2, ntq0 = (w >> 1) * 2;
  {
    int kk = kc * 256 + t;
    const float* pp = positions + ((size_t)b * SS + kk) * 3;
    float bump = amask[(size_t)b * SS + kk] ? 0.f : 1.0e4f;
    posk4[t] = make_float4(pp[0] + bump, pp[1], pp[2], 0.f);
  }
  float pqx[2], pqy[2], pqz[2];
#pragma unroll
  for (int ni = 0; ni < 2; ++ni) {
    const float* pp = positions + ((size_t)b * SS + q0 + (ntq0 + ni) * 16 + l15) * 3;
    pqx[ni] = pp[0]; pqy[ni] = pp[1]; pqz[ni] = pp[2];
  }
  __syncthreads();

  const floatx4 fz = {0.f, 0.f, 0.f, 0.f};
#pragma unroll 1
  for (int ki = 0; ki < 4; ++ki) {
    const int kt = kc * 256 + ki * 64;
    float d2m[2][4][2];
#pragma unroll
    for (int mi = 0; mi < 2; ++mi)
#pragma unroll
      for (int r = 0; r < 4; ++r) {
        int kl = (mtk0 + mi) * 16 + quad * 4 + r;
        float4 pk = posk4[ki * 64 + kl];
#pragma unroll
        for (int ni = 0; ni < 2; ++ni) {
          float dx = pqx[ni] - pk.x, dy = pqy[ni] - pk.y, dz = pqz[ni] - pk.z;
          d2m[mi][r][ni] = dx * dx + dy * dy + dz * dz;
        }
      }
    floatx4 am[2][2] = {{fz, fz}, {fz, fz}};
#pragma unroll 1
    for (int h = 0; h < NHD; ++h) {
      const size_t hb = (size_t)(b * NHD + h);
      short8 qfh[2][2], qfl[2][2], kfh[2][2], kfl[2][2];
#pragma unroll
      for (int ni = 0; ni < 2; ++ni)
#pragma unroll
        for (int ks = 0; ks < 2; ++ks) {
          size_t o =
              (hb * SS + q0 + (ntq0 + ni) * 16 + l15) * HD + ks * 32 + quad * 8;
          qfh[ni][ks] = *(const short8*)(qhi + o);
          qfl[ni][ks] = *(const short8*)(qlo + o);
        }
#pragma unroll
      for (int mi = 0; mi < 2; ++mi)
#pragma unroll
        for (int ks = 0; ks < 2; ++ks) {
          size_t o =
              (hb * SS + kt + (mtk0 + mi) * 16 + l15) * HD + ks * 32 + quad * 8;
          kfh[mi][ks] = *(const short8*)(khi + o);
          kfl[mi][ks] = *(const short8*)(klo + o);
        }
      float li[2];
#pragma unroll
      for (int ni = 0; ni < 2; ++ni)
        li[ni] = linv[hb * SS + q0 + (ntq0 + ni) * 16 + l15];

      floatx4 acc[2][2] = {{fz, fz}, {fz, fz}};
#pragma unroll
      for (int ks = 0; ks < 2; ++ks)
#pragma unroll
        for (int mi = 0; mi < 2; ++mi)
#pragma unroll
          for (int ni = 0; ni < 2; ++ni) {
            acc[mi][ni] = mfma16(kfh[mi][ks], qfh[ni][ks], acc[mi][ni]);
            acc[mi][ni] = mfma16(kfh[mi][ks], qfl[ni][ks], acc[mi][ni]);
            acc[mi][ni] = mfma16(kfl[mi][ks], qfh[ni][ks], acc[mi][ni]);
          }
#pragma unroll
      for (int mi = 0; mi < 2; ++mi)
#pragma unroll
        for (int ni = 0; ni < 2; ++ni)
#pragma unroll
          for (int r = 0; r < 4; ++r)
            am[mi][ni][r] +=
                __expf((acc[mi][ni][r] - d2m[mi][r][ni]) * 0.125f - CSHIFT) *
                li[ni];
    }  // h

    __syncthreads();  // Pm free (prior ki's reads done)
#pragma unroll
    for (int mi = 0; mi < 2; ++mi)
#pragma unroll
      for (int ni = 0; ni < 2; ++ni) {
        int q = (ntq0 + ni) * 16 + l15;
        int k0 = (mtk0 + mi) * 16 + quad * 4;
        *(float4*)&Pm[q * 68 + k0] =
            make_float4(am[mi][ni][0], am[mi][ni][1], am[mi][ni][2],
                        am[mi][ni][3]);
      }
    __syncthreads();
    {
      int q = t >> 2, c0 = (t & 3) * 16;
#pragma unroll
      for (int u = 0; u < 4; ++u) {
        float4 v = *(const float4*)&Pm[q * 68 + c0 + u * 4];
        v.x *= 0.125f; v.y *= 0.125f; v.z *= 0.125f; v.w *= 0.125f;
        *(float4*)&mean_out[((size_t)b * SS + q0 + q) * SS + kt + c0 + u * 4] = v;
      }
    }
  }  // ki
}

// ---------------------------------------------------------------------------
extern "C" void kernel_launch(void* const* d_in, const int* in_sizes, int n_in,
                              void* d_out, int out_size, void* d_ws,
                              size_t ws_size, hipStream_t stream) {
  const float* x         = (const float*)d_in[0];
  const float* positions = (const float*)d_in[1];
  const int*   amask     = (const int*)d_in[2];
  const float* w_qkv     = (const float*)d_in[3];
  const float* b_qkv     = (const float*)d_in[4];
  const float* w_out     = (const float*)d_in[5];
  const float* b_out     = (const float*)d_in[6];

  float* out      = (float*)d_out;                // [B,S,H]
  float* mean_out = out + (size_t)NB * SS * HH;   // [B,S,S]

  // ws (ushorts): xhi|xlo | wqh|wql | woh|wol | qhi|qlo|khi|klo|vhi | linv(f32)
  // ao hi/lo overlays xhi/xlo (x dead after QKV GEMMs). Total 63.2 MB.
  const size_t XE = (size_t)8192 * 512;  // 4,194,304
  const size_t WQ = (size_t)1536 * 512;
  const size_t WO = (size_t)512 * 512;
  const size_t QE = XE;
  unsigned short* W16 = (unsigned short*)d_ws;
  unsigned short* xhi = W16;
  unsigned short* xlo = W16 + XE;
  unsigned short* wqh = W16 + 2 * XE;
  unsigned short* wql = wqh + WQ;
  unsigned short* woh = wql + WQ;
  unsigned short* wol = woh + WO;
  unsigned short* qhi = wol + WO;
  unsigned short* qlo = qhi + QE;
  unsigned short* khi = qlo + QE;
  unsigned short* klo = khi + QE;
  unsigned short* vhi = klo + QE;
  float* linv = (float*)(vhi + QE);
  unsigned short* aohi = xhi;  // overlay
  unsigned short* aolo = xlo;
  unsigned short* wvh = wqh + (size_t)1024 * 512;  // V rows of w_qkv
  unsigned short* wvl = wql + (size_t)1024 * 512;

  dim3 blk(256);
  split_kernel<<<4096, blk, 0, stream>>>(x, xhi, xlo, 1048576);
  split_kernel<<<768, blk, 0, stream>>>(w_qkv, wqh, wql, 196608);
  split_kernel<<<256, blk, 0, stream>>>(w_out, woh, wol, 65536);
  qk_gemm_kernel<<<dim3(8, 64), blk, 0, stream>>>(wqh, wql, xhi, xlo, b_qkv,
                                                  qhi, qlo, khi, klo);
  v_gemm_kernel<<<dim3(4, 64), blk, 0, stream>>>(xhi, xlo, wvh, wvl, b_qkv,
                                                 vhi);
  attn_o_kernel<<<dim3(32, NB, NHD), blk, 0, stream>>>(
      qhi, qlo, khi, klo, vhi, positions, amask, aohi, aolo, linv);
  mean_kernel<<<dim3(32, NB, 8), blk, 0, stream>>>(qhi, qlo, khi, klo,
                                                   positions, amask, linv,
                                                   mean_out);
  out_gemm_kernel<<<dim3(4, 64), blk, 0, stream>>>(aohi, aolo, woh, wol, b_out,
                                                   out);
}